// Round 9
// baseline (257.903 us; speedup 1.0000x reference)
//
#include <hip/hip_runtime.h>

#define LPC_N 32
#define LPC_EPS 1e-5f
#define NREG 16                       // lags 0..15: f2 register-resident
#define NLDS (LPC_N + 1 - NREG)       // lags 16..32: per-wave LDS (17 lags)

typedef float f2 __attribute__((ext_vector_type(2)));

__device__ __forceinline__ f2 rcp2(f2 v) {
    f2 r;
    r.x = __builtin_amdgcn_rcpf(v.x);
    r.y = __builtin_amdgcn_rcpf(v.y);
    return r;
}

// R0-R8 synthesis. Fixed facts: memory term ~32us is irreducible (ideal
// traffic, L3 can't absorb the 131MB write: input+output > LLC, proven by
// R8's WRITE_SIZE==131072 with plain stores). VALU term halves with packed
// f2 math (R0/R6: 17us busy vs 32us scalar). Both f2 attempts died on
// residency, not math: R0 uncapped -> ~256 regs, 2 waves/SIMD; R6 cap=128 <
// honest ~135 -> scratch spills. This round sits between: f2 + 17 cold lags
// in LDS + __launch_bounds__(256,3):
//   budget 170 regs vs honest ~120 (lp[32]f2=64 + ac[16]f2=32 + temps ~20)
//   -> no spill pressure, no bloat; 3 waves/SIMD x 2 frames/lane = MORE
//   frame concurrency than R8 (1536 vs 1152 per CU) at HALF the issue cost.
// LDS: x/y split planes ([lag][0..63]=x, [lag][64..127]=y) so cold-lag reads
// are two clean ds_read_b32 (2-way = free) instead of a 4-way ds_read_b64.
// 34816 B/block -> 4 blocks/CU (LDS not binding at 3 waves/SIMD).
__global__ __launch_bounds__(256, 3) void levinson_kernel(
    const float* __restrict__ pAC,   // [N+1, T]
    float* __restrict__ out,         // [N, T]
    int T)
{
    __shared__ float smem[4 * NLDS * 128];   // 34816 B/block, per-wave chunks

    const int tid  = threadIdx.x;
    const int lane = tid & 63;
    const int wv   = tid >> 6;
    const int p    = blockIdx.x * blockDim.x + tid;   // frame-pair index
    const int TP   = T >> 1;
    if (p >= TP) return;

    float* wbuf = smem + wv * (NLDS * 128);

    // Stage cold lags (coalesced dwordx2 loads, 8 B/lane), split into x/y
    // planes. Each lane touches only its own column -> no barrier.
#pragma unroll
    for (int k = 0; k < NLDS; ++k) {
        f2 v = *(const f2*)(pAC + (size_t)(NREG + k) * T + 2 * (size_t)p);
        wbuf[k * 128 + lane]      = v.x;
        wbuf[k * 128 + 64 + lane] = v.y;
    }

    // Hot lags -> registers (used 17..32x each).
    f2 ac[NREG];
#pragma unroll
    for (int k = 0; k < NREG; ++k)
        ac[k] = *(const f2*)(pAC + (size_t)k * T + 2 * (size_t)p);

    // Fully unrolled => m is compile-time: folds to a VGPR-pair read or two
    // ds_read_b32 with immediate offsets.
    auto AC = [&](int m) -> f2 {
        if (m < NREG) return ac[m];
        int k = m - NREG;
        f2 r;
        r.x = wbuf[k * 128 + lane];
        r.y = wbuf[k * 128 + 64 + lane];
        return r;
    };

    f2 lp[LPC_N];
    f2 E = ac[0];

#pragma unroll
    for (int i = 0; i < LPC_N; ++i) {
        // rcp issued first: latency hides under the dot product.
        f2 invE = rcp2(E);

        // acc = ac[i+1] + sum_{j<i} lp[j]*ac[i-j], two independent FMA chains.
        f2 s0 = AC(i + 1);
        f2 s1 = {0.0f, 0.0f};
#pragma unroll
        for (int j = 0; j + 1 < i; j += 2) {
            s0 += lp[j]     * AC(i - j);
            s1 += lp[j + 1] * AC(i - j - 1);
        }
        if (i & 1) {                    // leftover j = i-1 when i is odd
            s0 += lp[i - 1] * ac[1];
        }
        f2 acc = s0 + s1;

        f2 ki = acc * invE;
        f2 c  = {1.0f, 1.0f};
        c -= ki * ki;
        c.x = fmaxf(c.x, LPC_EPS);
        c.y = fmaxf(c.y, LPC_EPS);
        E *= c;

        // lp[j] = lp[j] - ki*lp[i-1-j] from OLD lp: pairwise swap update.
#pragma unroll
        for (int j = 0; j < i - 1 - j; ++j) {
            f2 a = lp[j];
            f2 b = lp[i - 1 - j];
            lp[j]         = a - ki * b;
            lp[i - 1 - j] = b - ki * a;
        }
        if (i & 1) {
            int m = (i - 1) >> 1;       // self-paired middle element
            lp[m] = lp[m] - ki * lp[m];
        }
        lp[i] = -ki;
    }

    // Plain coalesced dwordx2 stores (R8 A/B: NT vs WB is noise; keep WB).
#pragma unroll
    for (int i = 0; i < LPC_N; ++i) {
        *(f2*)(out + (size_t)i * T + 2 * (size_t)p) = lp[i];
    }
}

extern "C" void kernel_launch(void* const* d_in, const int* in_sizes, int n_in,
                              void* d_out, int out_size, void* d_ws, size_t ws_size,
                              hipStream_t stream)
{
    const float* pAC = (const float*)d_in[0];
    float* out = (float*)d_out;
    int T = in_sizes[0] / (LPC_N + 1);   // 1048576

    int TP = T >> 1;                     // 524288 frame pairs
    int block = 256;
    int grid = (TP + block - 1) / block; // 2048 blocks
    levinson_kernel<<<grid, block, 0, stream>>>(pAC, out, T);
}